// Round 10
// baseline (316.004 us; speedup 1.0000x reference)
//
#include <hip/hip_runtime.h>

typedef unsigned short u16;
typedef u16 u16x4 __attribute__((ext_vector_type(4)));
typedef u16 u16x8 __attribute__((ext_vector_type(8)));
typedef __bf16 bf16x8 __attribute__((ext_vector_type(8)));
typedef float f32x4 __attribute__((ext_vector_type(4)));

#define GL2LDS(gp, lp)                                                          \
  __builtin_amdgcn_global_load_lds(                                             \
      (const __attribute__((address_space(1))) void*)(gp),                      \
      (__attribute__((address_space(3))) void*)(lp), 16, 0, 0)

__device__ __forceinline__ u16 f2bf(float f) {
  unsigned u = __builtin_bit_cast(unsigned, f);
  u += 0x7fffu + ((u >> 16) & 1u);
  return (u16)(u >> 16);
}

__device__ __forceinline__ float bf2f(u16 v) {
  unsigned u = ((unsigned)v) << 16;
  return __builtin_bit_cast(float, u);
}

__device__ __forceinline__ f32x4 mfma_bf16(u16x8 a, u16x8 b, f32x4 c) {
  return __builtin_amdgcn_mfma_f32_16x16x32_bf16(
      __builtin_bit_cast(bf16x8, a), __builtin_bit_cast(bf16x8, b), c, 0, 0, 0);
}

constexpr int BN_ = 8;      // batch
constexpr int S_ = 2048;    // seq
constexpr int D_ = 1024;    // embed
constexpr int EP = 272;     // epilogue staging stride (row step = +8 banks, conflict-free writes)

// ---------------------------------------------------------------- small kernels
__global__ __launch_bounds__(256) void cvt_bf16(const float* __restrict__ in,
                                                u16* __restrict__ out, int n8) {
  int i = blockIdx.x * blockDim.x + threadIdx.x;
  int stride = gridDim.x * blockDim.x;
  for (; i < n8; i += stride) {
    const float4* p = reinterpret_cast<const float4*>(in) + (size_t)i * 2;
    float4 a = p[0], b = p[1];
    u16x8 o;
    o[0] = f2bf(a.x); o[1] = f2bf(a.y); o[2] = f2bf(a.z); o[3] = f2bf(a.w);
    o[4] = f2bf(b.x); o[5] = f2bf(b.y); o[6] = f2bf(b.z); o[7] = f2bf(b.w);
    reinterpret_cast<u16x8*>(out)[i] = o;
  }
}

__global__ __launch_bounds__(256) void concat3(const float* __restrict__ a,
                                               const float* __restrict__ b,
                                               const float* __restrict__ c,
                                               float* __restrict__ o) {
  int i = blockIdx.x * 256 + threadIdx.x;
  if (i < 1024) o[i] = a[i];
  else if (i < 2048) o[i] = b[i - 1024];
  else if (i < 3072) o[i] = c[i - 2048];
}

// msk[r][c] = bf16(rot[r][c]^2); rinv[r] = 1 / max(sum_c rot^2, EPS^2)
__global__ __launch_bounds__(256) void mask_kernel(const float* __restrict__ rot,
                                                   u16* __restrict__ msk,
                                                   float* __restrict__ rinv) {
  int r = blockIdx.x, t = threadIdx.x;
  const float4* p = reinterpret_cast<const float4*>(rot + (size_t)r * S_);
  float4 a = p[t], b = p[t + 256];
  float ax = a.x * a.x, ay = a.y * a.y, az = a.z * a.z, aw = a.w * a.w;
  float bx = b.x * b.x, by = b.y * b.y, bz = b.z * b.z, bw = b.w * b.w;
  u16x4 oa, ob;
  oa[0] = f2bf(ax); oa[1] = f2bf(ay); oa[2] = f2bf(az); oa[3] = f2bf(aw);
  ob[0] = f2bf(bx); ob[1] = f2bf(by); ob[2] = f2bf(bz); ob[3] = f2bf(bw);
  u16* mrow = msk + (size_t)r * S_;
  *reinterpret_cast<u16x4*>(mrow + t * 4) = oa;
  *reinterpret_cast<u16x4*>(mrow + 1024 + t * 4) = ob;
  float s = ax + ay + az + aw + bx + by + bz + bw;
#pragma unroll
  for (int d = 1; d < 64; d <<= 1) s += __shfl_xor(s, d);
  __shared__ float wsum[4];
  if ((t & 63) == 0) wsum[t >> 6] = s;
  __syncthreads();
  if (t == 0) {
    float ss = wsum[0] + wsum[1] + wsum[2] + wsum[3];
    rinv[r] = 1.0f / fmaxf(ss, 1e-24f);
  }
}

// ---------------------------------------------------------------- 8-phase K-loop core
// 256x256 tile, BK=64, 8 waves (2M x 4N); LDS 128 KB: 2 buf x {A,B} x {k0,k1}
// regions of [256][32] u16. Linear DMA dest + inverse-swizzled global source +
// swizzled ds_read (st_16x32 family). vmcnt(6) at phases 4,8 only; never 0.
// Tail stages wrap (kt & (NK-1)): stage COUNTS stay uniform so the vmcnt
// landing guarantees hold in every iteration; wrapped junk lands only in
// regions that are never read again. Epilogues that reuse the LDS fence with
// __syncthreads() first (its implicit vmcnt(0) drains the junk).
template <int NK>
__device__ __forceinline__ void kloop8(const u16* __restrict__ Abase,
                                       const u16* __restrict__ Bbase,
                                       int sA, int sB, u16* sh,
                                       f32x4 (&acc)[8][4]) {
  const int t = threadIdx.x;
  const int lane = t & 63, w = t >> 6;
  const int wm = w >> 2, wn = w & 3;
  const int lr = lane & 15;
  const int sl = (lane >> 4) ^ (((lr >> 3) & 1) << 1);   // swizzled 16B slot
  const int aOff = (wm * 128 + lr) * 32 + sl * 8;        // u16, within (P,kk) region
  const int bOff = 16384 + (wn * 64 + lr) * 32 + sl * 8; // + B-op offset

  // stage source precompute (inverse swizzle on global address)
  const int tr = t ^ (((t >> 5) & 1) << 1);
  const u16* aSrc = Abase + (size_t)(tr >> 2) * sA + (tr & 3) * 8;
  const u16* bSrc = Bbase + (size_t)(tr >> 2) * sB + (tr & 3) * 8;
  const size_t a128 = (size_t)128 * sA, b128 = (size_t)128 * sB;
  u16* dBase = sh + t * 8;

  auto stage = [&](int P, int op, int kk, int kt) {
    kt &= (NK - 1);  // wrap at tail: uniform vmcnt counting, data unused
    const u16* s = (op ? bSrc : aSrc) + kt * 64 + kk * 32;
    u16* d = dBase + P * 32768 + op * 16384 + kk * 8192;
    GL2LDS(s, d);
    GL2LDS(s + (op ? b128 : a128), d + 4096);
  };

  u16x8 bf[4];

#define PHASE(P, kk, mh, sP, sOp, sKk, sKt, vm)                                  \
  do {                                                                           \
    const u16* ap_ = sh + (P) * 32768 + (kk) * 8192 + aOff;                      \
    u16x8 af_[4];                                                                \
    _Pragma("unroll")                                                            \
    for (int i_ = 0; i_ < 4; ++i_)                                               \
      af_[i_] = *reinterpret_cast<const u16x8*>(ap_ + ((mh) * 4 + i_) * 512);    \
    if ((mh) == 0) {                                                             \
      const u16* bp_ = sh + (P) * 32768 + (kk) * 8192 + bOff;                    \
      _Pragma("unroll")                                                          \
      for (int j_ = 0; j_ < 4; ++j_)                                             \
        bf[j_] = *reinterpret_cast<const u16x8*>(bp_ + j_ * 512);                \
    }                                                                            \
    stage(sP, sOp, sKk, sKt);                                                    \
    asm volatile("s_barrier" ::: "memory");                                      \
    __builtin_amdgcn_s_setprio(1);                                               \
    _Pragma("unroll")                                                            \
    for (int i_ = 0; i_ < 4; ++i_)                                               \
      _Pragma("unroll")                                                          \
      for (int j_ = 0; j_ < 4; ++j_)                                             \
        acc[(mh) * 4 + i_][j_] = mfma_bf16(af_[i_], bf[j_], acc[(mh) * 4 + i_][j_]); \
    __builtin_amdgcn_s_setprio(0);                                               \
    if (vm) asm volatile("s_waitcnt vmcnt(6)" ::: "memory");                     \
    asm volatile("s_barrier" ::: "memory");                                      \
  } while (0)

  // prologue: K0 fully, K1 all but A.k1 (staged by ph1); allow last 3 stages in flight
  stage(0, 1, 0, 0); stage(0, 0, 0, 0); stage(0, 1, 1, 0); stage(0, 0, 1, 0);
  stage(1, 1, 0, 1); stage(1, 0, 0, 1); stage(1, 1, 1, 1);
  asm volatile("s_waitcnt vmcnt(6)" ::: "memory");
  asm volatile("s_barrier" ::: "memory");

  for (int j2 = 0; j2 < NK / 2; ++j2) {
    const int kb = 2 * j2;
    PHASE(0, 0, 0, 1, 0, 1, kb + 1, false);  // stage P1.A.k1 <- ktile kb+1
    PHASE(0, 0, 1, 0, 1, 0, kb + 2, false);  // stage P0.B.k0 <- kb+2
    PHASE(0, 1, 0, 0, 0, 0, kb + 2, false);  // stage P0.A.k0 <- kb+2
    PHASE(0, 1, 1, 0, 1, 1, kb + 2, true);   // stage P0.B.k1 <- kb+2, vmcnt(6)
    PHASE(1, 0, 0, 0, 0, 1, kb + 2, false);  // stage P0.A.k1 <- kb+2
    PHASE(1, 0, 1, 1, 1, 0, kb + 3, false);  // stage P1.B.k0 <- kb+3
    PHASE(1, 1, 0, 1, 0, 0, kb + 3, false);  // stage P1.A.k0 <- kb+3
    PHASE(1, 1, 1, 1, 1, 1, kb + 3, true);   // stage P1.B.k1 <- kb+3, vmcnt(6)
  }
#undef PHASE
}

// ---------------------------------------------------------------- fused QKV (256^2, 8-phase)
// C = xb @ wcat^T + bcat; col-tiles 0-3 -> q, 4-7 -> k, 8-11 -> v (transposed to vt)
__global__ __launch_bounds__(512, 2)
void gemm_qkv8(const u16* __restrict__ xb, const u16* __restrict__ wcat,
               const float* __restrict__ bcat, u16* __restrict__ qb,
               u16* __restrict__ kb, u16* __restrict__ vtb) {
  __shared__ alignas(16) u16 sh[65536];
  const int lin = blockIdx.x;
  const int swz = (lin & 7) * 96 + (lin >> 3);   // 768 blocks, 8 XCDs
  const int rt = swz / 12, ct = swz - rt * 12;
  const int rowBase = rt << 8, colBase = ct << 8;

  f32x4 acc[8][4] = {};
  kloop8<16>(xb + (size_t)rowBase * D_, wcat + (size_t)colBase * D_, D_, D_, sh, acc);

  const int t = threadIdx.x;
  const int lane = t & 63, w = t >> 6;
  const int wm = w >> 2, wn = w & 3;
  const int lrow4 = (lane >> 4) * 4, lcol = lane & 15;

  float bias[4];
#pragma unroll
  for (int j = 0; j < 4; ++j) bias[j] = bcat[colBase + wn * 64 + j * 16 + lcol];

  const int cls = colBase >> 10;  // 0=q, 1=k, 2=v
  const int ccol = colBase & 1023;
  if (cls < 2) {
    // LDS-staged vectorized epilogue, two 128-row passes
    __syncthreads();  // drains vmcnt(0): in-flight wrap-stage junk lands before reuse
    u16* out16 = (cls == 0) ? qb : kb;
#pragma unroll
    for (int h = 0; h < 2; ++h) {
      if (wm == h) {
#pragma unroll
        for (int i = 0; i < 8; ++i)
#pragma unroll
          for (int jj = 0; jj < 4; ++jj) {
            int rloc = i * 16 + lrow4 + jj;
#pragma unroll
            for (int j = 0; j < 4; ++j)
              sh[rloc * EP + wn * 64 + j * 16 + lcol] = f2bf(acc[i][j][jj] + bias[j]);
          }
      }
      __syncthreads();
#pragma unroll
      for (int r2 = 0; r2 < 8; ++r2) {
        int row = r2 * 16 + (t >> 5), chunk = t & 31;
        u16x8 v = *reinterpret_cast<const u16x8*>(sh + row * EP + chunk * 8);
        *reinterpret_cast<u16x8*>(out16 + (size_t)(rowBase + h * 128 + row) * D_ +
                                  ccol + chunk * 8) = v;
      }
      __syncthreads();
    }
  } else {
    // v: transpose 256x256 tile through LDS in two 128-row passes
    __syncthreads();  // drains vmcnt(0)
    u16 (*Ts)[136] = reinterpret_cast<u16(*)[136]>(sh);
    const int bq = rowBase >> 11, s0 = rowBase & (S_ - 1);
#pragma unroll
    for (int h = 0; h < 2; ++h) {
      if (wm == h) {
#pragma unroll
        for (int i = 0; i < 8; ++i)
#pragma unroll
          for (int jj = 0; jj < 4; ++jj)
#pragma unroll
            for (int j = 0; j < 4; ++j)
              Ts[wn * 64 + j * 16 + lcol][i * 16 + lrow4 + jj] =
                  f2bf(acc[i][j][jj] + bias[j]);
      }
      __syncthreads();
      const int col = t >> 1, ro = (t & 1) * 64;
      u16* dst = vtb + (size_t)bq * D_ * S_ + (size_t)(ccol + col) * S_ +
                 s0 + h * 128 + ro;
      const u16* srcp = &Ts[col][ro];
#pragma unroll
      for (int k2 = 0; k2 < 8; ++k2)
        *reinterpret_cast<u16x8*>(dst + k2 * 8) =
            *reinterpret_cast<const u16x8*>(srcp + k2 * 8);
      __syncthreads();
    }
  }
}

// ---------------------------------------------------------------- scores (256^2, 8-phase)
// logits = q @ k^T / 32; hyb = exp(l)*msk (bf16, unnormalized); Z[b,row] += sum exp(l)
__global__ __launch_bounds__(512, 2)
void score8(const u16* __restrict__ qb, const u16* __restrict__ kb,
            const u16* __restrict__ msk, u16* __restrict__ hyb,
            float* __restrict__ Z) {
  __shared__ alignas(16) u16 sh[65536];
  const int lin = blockIdx.x;
  const int swz = (lin & 7) * 64 + (lin >> 3);   // 512 blocks; one batch per XCD
  const int b = swz >> 6, rt = (swz >> 3) & 7, ct = swz & 7;
  const int rowBase = rt << 8, colBase = ct << 8;

  f32x4 acc[8][4] = {};
  kloop8<16>(qb + ((size_t)(b * S_ + rowBase)) * D_,
             kb + ((size_t)(b * S_ + colBase)) * D_, D_, D_, sh, acc);

  const int t = threadIdx.x;
  const int lane = t & 63, w = t >> 6;
  const int wm = w >> 2, wn = w & 3;
  const int lrow4 = (lane >> 4) * 4, lcol = lane & 15;

  float zacc[8][4] = {};

  // LDS-staged epilogue: exp*msk -> LDS, coalesced nontemporal u16x8 stores
  __syncthreads();  // drains vmcnt(0): wrap-stage junk lands before LDS reuse
#pragma unroll
  for (int h = 0; h < 2; ++h) {
    if (wm == h) {
#pragma unroll
      for (int i = 0; i < 8; ++i)
#pragma unroll
        for (int jj = 0; jj < 4; ++jj) {
          const int rloc = i * 16 + lrow4 + jj;
          const size_t mrow = (size_t)(rowBase + h * 128 + rloc) * S_;
#pragma unroll
          for (int j = 0; j < 4; ++j) {
            const int cloc = wn * 64 + j * 16 + lcol;
            float e = __expf(acc[i][j][jj] * 0.03125f);
            zacc[i][jj] += e;
            sh[rloc * EP + cloc] = f2bf(e * bf2f(msk[mrow + colBase + cloc]));
          }
        }
    }
    __syncthreads();
#pragma unroll
    for (int r2 = 0; r2 < 8; ++r2) {
      int row = r2 * 16 + (t >> 5), chunk = t & 31;
      u16x8 v = *reinterpret_cast<const u16x8*>(sh + row * EP + chunk * 8);
      __builtin_nontemporal_store(
          v, reinterpret_cast<u16x8*>(hyb +
                                      ((size_t)(b * S_ + rowBase + h * 128 + row)) * S_ +
                                      colBase + chunk * 8));
    }
    __syncthreads();
  }

  // reduce Z across the 16 column-lanes, one atomic per row
#pragma unroll
  for (int i = 0; i < 8; ++i) {
#pragma unroll
    for (int jj = 0; jj < 4; ++jj) {
      float v = zacc[i][jj];
#pragma unroll
      for (int d = 1; d < 16; d <<= 1) v += __shfl_xor(v, d);
      if (lcol == 0) {
        int row = rowBase + wm * 128 + i * 16 + lrow4 + jj;
        atomicAdd(&Z[b * S_ + row], v);
      }
    }
  }
}

// ---------------------------------------------------------------- PV (256^2, 8-phase)
// out[b] = (hyb[b] @ vt[b]) * rinv[r] / Z[b][r]; LDS-staged f32x4 epilogue.
__global__ __launch_bounds__(512, 2)
void gemm_pv8(const u16* __restrict__ hyb, const u16* __restrict__ vtb,
              const float* __restrict__ Z, const float* __restrict__ rinv,
              float* __restrict__ outp) {
  __shared__ alignas(16) u16 sh[65536];
  const int lin = blockIdx.x;
  const int swz = (lin & 7) * 32 + (lin >> 3);   // 256 blocks; one batch per XCD
  const int b = swz >> 5, rt = (swz >> 2) & 7, ct = swz & 3;
  const int rowBase = rt << 8, colBase = ct << 8;

  f32x4 acc[8][4] = {};
  kloop8<32>(hyb + (size_t)b * S_ * S_ + (size_t)rowBase * S_,
             vtb + (size_t)b * D_ * S_ + (size_t)colBase * S_, S_, S_, sh, acc);

  const int t = threadIdx.x;
  const int lane = t & 63, w = t >> 6;
  const int wm = w >> 2, wn = w & 3;
  const int lrow4 = (lane >> 4) * 4, lcol = lane & 15;

  float* outf = outp + (size_t)b * S_ * D_;
  const float* Zb = Z + (size_t)b * S_;
  float* Tf = reinterpret_cast<float*>(sh);  // [64][EP] f32 quarters

  __syncthreads();  // drains vmcnt(0) before LDS reuse
#pragma unroll
  for (int q = 0; q < 4; ++q) {
    if (wm == (q >> 1)) {
#pragma unroll
      for (int i2 = 0; i2 < 4; ++i2) {
        const int i = (q & 1) * 4 + i2;
#pragma unroll
        for (int jj = 0; jj < 4; ++jj) {
          const int rl = i2 * 16 + lrow4 + jj;
          const int r = rowBase + q * 64 + rl;
          const float rz = rinv[r] / Zb[r];
#pragma unroll
          for (int j = 0; j < 4; ++j)
            Tf[rl * EP + wn * 64 + j * 16 + lcol] = acc[i][j][jj] * rz;
        }
      }
    }
    __syncthreads();
#pragma unroll
    for (int r2 = 0; r2 < 8; ++r2) {
      int rl = r2 * 8 + (t >> 6), chunk = t & 63;
      f32x4 v = *reinterpret_cast<const f32x4*>(Tf + rl * EP + chunk * 4);
      __builtin_nontemporal_store(
          v, reinterpret_cast<f32x4*>(outf + (size_t)(rowBase + q * 64 + rl) * D_ +
                                      colBase + chunk * 4));
    }
    __syncthreads();
  }
}

// ---------------------------------------------------------------- launch
extern "C" void kernel_launch(void* const* d_in, const int* in_sizes, int n_in,
                              void* d_out, int out_size, void* d_ws, size_t ws_size,
                              hipStream_t stream) {
  const float* x = (const float*)d_in[0];
  const float* Wq = (const float*)d_in[1];
  const float* bq = (const float*)d_in[2];
  const float* Wk = (const float*)d_in[3];
  const float* bk = (const float*)d_in[4];
  const float* Wv = (const float*)d_in[5];
  const float* bv = (const float*)d_in[6];
  const float* rot = (const float*)d_in[7];

  char* ws = (char*)d_ws;
  size_t off = 0;
  auto take = [&](size_t bytes) {
    char* p = ws + off;
    off += (bytes + 255) & ~(size_t)255;
    return p;
  };
  u16* xb = (u16*)take((size_t)BN_ * S_ * D_ * 2);        // 32 MB
  u16* wcat = (u16*)take((size_t)3 * D_ * D_ * 2);        // 6 MB (Wq|Wk|Wv)
  float* bcat = (float*)take((size_t)3 * D_ * 4);
  u16* qb = (u16*)take((size_t)BN_ * S_ * D_ * 2);        // 32 MB
  u16* kbuf = (u16*)take((size_t)BN_ * S_ * D_ * 2);      // 32 MB
  u16* vtb = (u16*)take((size_t)BN_ * S_ * D_ * 2);       // 32 MB (B,D,S)
  u16* hyb = (u16*)take((size_t)BN_ * S_ * S_ * 2);       // 64 MB
  u16* msk = (u16*)take((size_t)S_ * S_ * 2);             // 8.4 MB
  float* Zb = (float*)take((size_t)BN_ * S_ * 4);
  float* rinv = (float*)take((size_t)S_ * 4);

  (void)hipMemsetAsync(Zb, 0, (size_t)BN_ * S_ * 4, stream);

  cvt_bf16<<<2048, 256, 0, stream>>>(x, xb, BN_ * S_ * D_ / 8);
  cvt_bf16<<<512, 256, 0, stream>>>(Wq, wcat, D_ * D_ / 8);
  cvt_bf16<<<512, 256, 0, stream>>>(Wk, wcat + (size_t)D_ * D_, D_ * D_ / 8);
  cvt_bf16<<<512, 256, 0, stream>>>(Wv, wcat + (size_t)2 * D_ * D_, D_ * D_ / 8);
  concat3<<<12, 256, 0, stream>>>(bq, bk, bv, bcat);
  mask_kernel<<<S_, 256, 0, stream>>>(rot, msk, rinv);

  gemm_qkv8<<<768, 512, 0, stream>>>(xb, wcat, bcat, qb, kbuf, vtb);

  score8<<<512, 512, 0, stream>>>(qb, kbuf, msk, hyb, Zb);

  gemm_pv8<<<256, 512, 0, stream>>>(hyb, vtb, Zb, rinv, (float*)d_out);
}

// Round 11
// 295.859 us; speedup vs baseline: 1.0681x; 1.0681x over previous
//
#include <hip/hip_runtime.h>

typedef unsigned short u16;
typedef u16 u16x4 __attribute__((ext_vector_type(4)));
typedef u16 u16x8 __attribute__((ext_vector_type(8)));
typedef __bf16 bf16x8 __attribute__((ext_vector_type(8)));
typedef float f32x4 __attribute__((ext_vector_type(4)));

#define GL2LDS(gp, lp)                                                          \
  __builtin_amdgcn_global_load_lds(                                             \
      (const __attribute__((address_space(1))) void*)(gp),                      \
      (__attribute__((address_space(3))) void*)(lp), 16, 0, 0)

__device__ __forceinline__ u16 f2bf(float f) {
  unsigned u = __builtin_bit_cast(unsigned, f);
  u += 0x7fffu + ((u >> 16) & 1u);
  return (u16)(u >> 16);
}

__device__ __forceinline__ float bf2f(u16 v) {
  unsigned u = ((unsigned)v) << 16;
  return __builtin_bit_cast(float, u);
}

__device__ __forceinline__ f32x4 mfma_bf16(u16x8 a, u16x8 b, f32x4 c) {
  return __builtin_amdgcn_mfma_f32_16x16x32_bf16(
      __builtin_bit_cast(bf16x8, a), __builtin_bit_cast(bf16x8, b), c, 0, 0, 0);
}

constexpr int BN_ = 8;      // batch
constexpr int S_ = 2048;    // seq
constexpr int D_ = 1024;    // embed

// ---------------------------------------------------------------- small kernels
__global__ __launch_bounds__(256) void cvt_bf16(const float* __restrict__ in,
                                                u16* __restrict__ out, int n8) {
  int i = blockIdx.x * blockDim.x + threadIdx.x;
  int stride = gridDim.x * blockDim.x;
  for (; i < n8; i += stride) {
    const float4* p = reinterpret_cast<const float4*>(in) + (size_t)i * 2;
    float4 a = p[0], b = p[1];
    u16x8 o;
    o[0] = f2bf(a.x); o[1] = f2bf(a.y); o[2] = f2bf(a.z); o[3] = f2bf(a.w);
    o[4] = f2bf(b.x); o[5] = f2bf(b.y); o[6] = f2bf(b.z); o[7] = f2bf(b.w);
    reinterpret_cast<u16x8*>(out)[i] = o;
  }
}

// converts Wq|Wk|Wv -> wcat (bf16) and concats biases -> bcat in ONE dispatch
__global__ __launch_bounds__(256) void cvt_wb(const float* __restrict__ Wq,
                                              const float* __restrict__ Wk,
                                              const float* __restrict__ Wv,
                                              const float* __restrict__ bq,
                                              const float* __restrict__ bk,
                                              const float* __restrict__ bv,
                                              u16* __restrict__ wcat,
                                              float* __restrict__ bcat) {
  const int bid = blockIdx.x, t = threadIdx.x;
  if (bid < 1536) {
    const int idx = bid * 256 + t;        // u16x8 index, 0..393215
    const int w = idx >> 17;              // which weight (131072 u16x8 each)
    const int off = idx & 131071;
    const float* src = (w == 0) ? Wq : (w == 1) ? Wk : Wv;
    const float4* p = reinterpret_cast<const float4*>(src) + (size_t)off * 2;
    float4 a = p[0], b = p[1];
    u16x8 o;
    o[0] = f2bf(a.x); o[1] = f2bf(a.y); o[2] = f2bf(a.z); o[3] = f2bf(a.w);
    o[4] = f2bf(b.x); o[5] = f2bf(b.y); o[6] = f2bf(b.z); o[7] = f2bf(b.w);
    reinterpret_cast<u16x8*>(wcat)[idx] = o;
  } else {
    const int j = (bid - 1536) * 256 + t;  // 0..3071
    bcat[j] = (j < 1024) ? bq[j] : (j < 2048) ? bk[j - 1024] : bv[j - 2048];
  }
}

// msk[r][c] = bf16(rot[r][c]^2); rinv[r] = 1 / max(sum_c rot^2, EPS^2)
__global__ __launch_bounds__(256) void mask_kernel(const float* __restrict__ rot,
                                                   u16* __restrict__ msk,
                                                   float* __restrict__ rinv) {
  int r = blockIdx.x, t = threadIdx.x;
  const float4* p = reinterpret_cast<const float4*>(rot + (size_t)r * S_);
  float4 a = p[t], b = p[t + 256];
  float ax = a.x * a.x, ay = a.y * a.y, az = a.z * a.z, aw = a.w * a.w;
  float bx = b.x * b.x, by = b.y * b.y, bz = b.z * b.z, bw = b.w * b.w;
  u16x4 oa, ob;
  oa[0] = f2bf(ax); oa[1] = f2bf(ay); oa[2] = f2bf(az); oa[3] = f2bf(aw);
  ob[0] = f2bf(bx); ob[1] = f2bf(by); ob[2] = f2bf(bz); ob[3] = f2bf(bw);
  u16* mrow = msk + (size_t)r * S_;
  *reinterpret_cast<u16x4*>(mrow + t * 4) = oa;
  *reinterpret_cast<u16x4*>(mrow + 1024 + t * 4) = ob;
  float s = ax + ay + az + aw + bx + by + bz + bw;
#pragma unroll
  for (int d = 1; d < 64; d <<= 1) s += __shfl_xor(s, d);
  __shared__ float wsum[4];
  if ((t & 63) == 0) wsum[t >> 6] = s;
  __syncthreads();
  if (t == 0) {
    float ss = wsum[0] + wsum[1] + wsum[2] + wsum[3];
    rinv[r] = 1.0f / fmaxf(ss, 1e-24f);
  }
}

// ---------------------------------------------------------------- 8-phase K-loop core
// 256x256 tile, BK=64, 8 waves (2M x 4N); LDS 128 KB: 2 buf x {A,B} x {k0,k1}
// regions of [256][32] u16. Linear DMA dest + inverse-swizzled global source +
// swizzled ds_read (st_16x32 family). vmcnt(6) at phases 4,8 only; never 0.
// stage() is issued FIRST in each phase (max in-flight head start toward its
// vmcnt deadline). Tail stages wrap (kt & (NK-1)): stage COUNTS stay uniform so
// the vmcnt landing guarantees hold; wrapped junk lands only in regions never
// read again (epilogues reusing LDS fence with __syncthreads(), whose implicit
// vmcnt(0) drains the junk first).
template <int NK>
__device__ __forceinline__ void kloop8(const u16* __restrict__ Abase,
                                       const u16* __restrict__ Bbase,
                                       int sA, int sB, u16* sh,
                                       f32x4 (&acc)[8][4]) {
  const int t = threadIdx.x;
  const int lane = t & 63, w = t >> 6;
  const int wm = w >> 2, wn = w & 3;
  const int lr = lane & 15;
  const int sl = (lane >> 4) ^ (((lr >> 3) & 1) << 1);   // swizzled 16B slot
  const int aOff = (wm * 128 + lr) * 32 + sl * 8;        // u16, within (P,kk) region
  const int bOff = 16384 + (wn * 64 + lr) * 32 + sl * 8; // + B-op offset

  // stage source precompute (inverse swizzle on global address)
  const int tr = t ^ (((t >> 5) & 1) << 1);
  const u16* aSrc = Abase + (size_t)(tr >> 2) * sA + (tr & 3) * 8;
  const u16* bSrc = Bbase + (size_t)(tr >> 2) * sB + (tr & 3) * 8;
  const size_t a128 = (size_t)128 * sA, b128 = (size_t)128 * sB;
  u16* dBase = sh + t * 8;

  auto stage = [&](int P, int op, int kk, int kt) {
    kt &= (NK - 1);  // wrap at tail: uniform vmcnt counting, data unused
    const u16* s = (op ? bSrc : aSrc) + kt * 64 + kk * 32;
    u16* d = dBase + P * 32768 + op * 16384 + kk * 8192;
    GL2LDS(s, d);
    GL2LDS(s + (op ? b128 : a128), d + 4096);
  };

  u16x8 bf[4];

#define PHASE(P, kk, mh, sP, sOp, sKk, sKt, vm)                                  \
  do {                                                                           \
    stage(sP, sOp, sKk, sKt);                                                    \
    const u16* ap_ = sh + (P) * 32768 + (kk) * 8192 + aOff;                      \
    u16x8 af_[4];                                                                \
    _Pragma("unroll")                                                            \
    for (int i_ = 0; i_ < 4; ++i_)                                               \
      af_[i_] = *reinterpret_cast<const u16x8*>(ap_ + ((mh) * 4 + i_) * 512);    \
    if ((mh) == 0) {                                                             \
      const u16* bp_ = sh + (P) * 32768 + (kk) * 8192 + bOff;                    \
      _Pragma("unroll")                                                          \
      for (int j_ = 0; j_ < 4; ++j_)                                             \
        bf[j_] = *reinterpret_cast<const u16x8*>(bp_ + j_ * 512);                \
    }                                                                            \
    asm volatile("s_barrier" ::: "memory");                                      \
    __builtin_amdgcn_s_setprio(1);                                               \
    _Pragma("unroll")                                                            \
    for (int i_ = 0; i_ < 4; ++i_)                                               \
      _Pragma("unroll")                                                          \
      for (int j_ = 0; j_ < 4; ++j_)                                             \
        acc[(mh) * 4 + i_][j_] = mfma_bf16(af_[i_], bf[j_], acc[(mh) * 4 + i_][j_]); \
    __builtin_amdgcn_s_setprio(0);                                               \
    if (vm) asm volatile("s_waitcnt vmcnt(6)" ::: "memory");                     \
    asm volatile("s_barrier" ::: "memory");                                      \
  } while (0)

  // prologue: K0 fully, K1 all but A.k1 (staged by ph1); allow last 3 stages in flight
  stage(0, 1, 0, 0); stage(0, 0, 0, 0); stage(0, 1, 1, 0); stage(0, 0, 1, 0);
  stage(1, 1, 0, 1); stage(1, 0, 0, 1); stage(1, 1, 1, 1);
  asm volatile("s_waitcnt vmcnt(6)" ::: "memory");
  asm volatile("s_barrier" ::: "memory");

  for (int j2 = 0; j2 < NK / 2; ++j2) {
    const int kb = 2 * j2;
    PHASE(0, 0, 0, 1, 0, 1, kb + 1, false);  // stage P1.A.k1 <- ktile kb+1
    PHASE(0, 0, 1, 0, 1, 0, kb + 2, false);  // stage P0.B.k0 <- kb+2
    PHASE(0, 1, 0, 0, 0, 0, kb + 2, false);  // stage P0.A.k0 <- kb+2
    PHASE(0, 1, 1, 0, 1, 1, kb + 2, true);   // stage P0.B.k1 <- kb+2, vmcnt(6)
    PHASE(1, 0, 0, 0, 0, 1, kb + 2, false);  // stage P0.A.k1 <- kb+2
    PHASE(1, 0, 1, 1, 1, 0, kb + 3, false);  // stage P1.B.k0 <- kb+3
    PHASE(1, 1, 0, 1, 0, 0, kb + 3, false);  // stage P1.A.k0 <- kb+3
    PHASE(1, 1, 1, 1, 1, 1, kb + 3, true);   // stage P1.B.k1 <- kb+3, vmcnt(6)
  }
#undef PHASE
}

// ---------------------------------------------------------------- fused QKV (256^2, 8-phase)
// C = xb @ wcat^T + bcat; col-tiles 0-3 -> q, 4-7 -> k, 8-11 -> v (transposed to vt)
__global__ __launch_bounds__(512, 2)
void gemm_qkv8(const u16* __restrict__ xb, const u16* __restrict__ wcat,
               const float* __restrict__ bcat, u16* __restrict__ qb,
               u16* __restrict__ kb, u16* __restrict__ vtb) {
  __shared__ alignas(16) u16 sh[65536];
  const int lin = blockIdx.x;
  const int swz = (lin & 7) * 96 + (lin >> 3);   // 768 blocks, 8 XCDs
  const int rt = swz / 12, ct = swz - rt * 12;
  const int rowBase = rt << 8, colBase = ct << 8;

  f32x4 acc[8][4] = {};
  kloop8<16>(xb + (size_t)rowBase * D_, wcat + (size_t)colBase * D_, D_, D_, sh, acc);

  const int t = threadIdx.x;
  const int lane = t & 63, w = t >> 6;
  const int wm = w >> 2, wn = w & 3;
  const int lrow4 = (lane >> 4) * 4, lcol = lane & 15;

  float bias[4];
#pragma unroll
  for (int j = 0; j < 4; ++j) bias[j] = bcat[colBase + wn * 64 + j * 16 + lcol];

  const int cls = colBase >> 10;  // 0=q, 1=k, 2=v
  const int ccol = colBase & 1023;
  if (cls < 2) {
    u16* out16 = (cls == 0) ? qb : kb;
#pragma unroll
    for (int i = 0; i < 8; ++i) {
#pragma unroll
      for (int jj = 0; jj < 4; ++jj) {
        int r = rowBase + wm * 128 + i * 16 + lrow4 + jj;
#pragma unroll
        for (int j = 0; j < 4; ++j) {
          int c = ccol + wn * 64 + j * 16 + lcol;
          out16[(size_t)r * D_ + c] = f2bf(acc[i][j][jj] + bias[j]);
        }
      }
    }
  } else {
    // v: transpose 256x256 tile through LDS in two 128-row passes
    __syncthreads();  // drains vmcnt(0): in-flight wrap-stage junk lands before reuse
    u16 (*Ts)[136] = reinterpret_cast<u16(*)[136]>(sh);
    const int bq = rowBase >> 11, s0 = rowBase & (S_ - 1);
#pragma unroll
    for (int h = 0; h < 2; ++h) {
      if (wm == h) {
#pragma unroll
        for (int i = 0; i < 8; ++i)
#pragma unroll
          for (int jj = 0; jj < 4; ++jj)
#pragma unroll
            for (int j = 0; j < 4; ++j)
              Ts[wn * 64 + j * 16 + lcol][i * 16 + lrow4 + jj] =
                  f2bf(acc[i][j][jj] + bias[j]);
      }
      __syncthreads();
      const int col = t >> 1, ro = (t & 1) * 64;
      u16* dst = vtb + (size_t)bq * D_ * S_ + (size_t)(ccol + col) * S_ +
                 s0 + h * 128 + ro;
      const u16* srcp = &Ts[col][ro];
#pragma unroll
      for (int k2 = 0; k2 < 8; ++k2)
        *reinterpret_cast<u16x8*>(dst + k2 * 8) =
            *reinterpret_cast<const u16x8*>(srcp + k2 * 8);
      __syncthreads();
    }
  }
}

// ---------------------------------------------------------------- scores (256^2, 8-phase)
// logits = q @ k^T / 32; hyb = exp(l)*msk (bf16, unnormalized); Z[b,row] += sum exp(l)
__global__ __launch_bounds__(512, 2)
void score8(const u16* __restrict__ qb, const u16* __restrict__ kb,
            const u16* __restrict__ msk, u16* __restrict__ hyb,
            float* __restrict__ Z) {
  __shared__ alignas(16) u16 sh[65536];
  const int lin = blockIdx.x;
  const int swz = (lin & 7) * 64 + (lin >> 3);   // 512 blocks; one batch per XCD
  const int b = swz >> 6, rt = (swz >> 3) & 7, ct = swz & 7;
  const int rowBase = rt << 8, colBase = ct << 8;

  f32x4 acc[8][4] = {};
  kloop8<16>(qb + ((size_t)(b * S_ + rowBase)) * D_,
             kb + ((size_t)(b * S_ + colBase)) * D_, D_, D_, sh, acc);

  const int t = threadIdx.x;
  const int lane = t & 63, w = t >> 6;
  const int wm = w >> 2, wn = w & 3;
  const int lrow4 = (lane >> 4) * 4, lcol = lane & 15;

#pragma unroll
  for (int i = 0; i < 8; ++i) {
    const int rowL = rowBase + wm * 128 + i * 16 + lrow4;
    f32x4 zrow = {0.f, 0.f, 0.f, 0.f};
#pragma unroll
    for (int j = 0; j < 4; ++j) {
      const int col = colBase + wn * 64 + j * 16 + lcol;
#pragma unroll
      for (int jj = 0; jj < 4; ++jj) {
        const int row = rowL + jj;
        float e = __expf(acc[i][j][jj] * 0.03125f);
        hyb[((size_t)(b * S_ + row)) * S_ + col] =
            f2bf(e * bf2f(msk[(size_t)row * S_ + col]));
        zrow[jj] += e;
      }
    }
#pragma unroll
    for (int d = 1; d < 16; d <<= 1) {
      zrow[0] += __shfl_xor(zrow[0], d);
      zrow[1] += __shfl_xor(zrow[1], d);
      zrow[2] += __shfl_xor(zrow[2], d);
      zrow[3] += __shfl_xor(zrow[3], d);
    }
    if (lcol == 0) {
#pragma unroll
      for (int jj = 0; jj < 4; ++jj)
        atomicAdd(&Z[b * S_ + rowL + jj], zrow[jj]);
    }
  }
}

// ---------------------------------------------------------------- PV (256^2, 8-phase)
// out[b] = (hyb[b] @ vt[b]^T-layout) * rinv[r] / Z[b][r]
__global__ __launch_bounds__(512, 2)
void gemm_pv8(const u16* __restrict__ hyb, const u16* __restrict__ vtb,
              const float* __restrict__ Z, const float* __restrict__ rinv,
              float* __restrict__ outp) {
  __shared__ alignas(16) u16 sh[65536];
  const int lin = blockIdx.x;
  const int swz = (lin & 7) * 32 + (lin >> 3);   // 256 blocks; one batch per XCD
  const int b = swz >> 5, rt = (swz >> 2) & 7, ct = swz & 3;
  const int rowBase = rt << 8, colBase = ct << 8;

  f32x4 acc[8][4] = {};
  kloop8<32>(hyb + (size_t)b * S_ * S_ + (size_t)rowBase * S_,
             vtb + (size_t)b * D_ * S_ + (size_t)colBase * S_, S_, S_, sh, acc);

  const int t = threadIdx.x;
  const int lane = t & 63, w = t >> 6;
  const int wm = w >> 2, wn = w & 3;
  const int lrow4 = (lane >> 4) * 4, lcol = lane & 15;

  float* outf = outp + (size_t)b * S_ * D_;
  const float* Zb = Z + (size_t)b * S_;
#pragma unroll
  for (int i = 0; i < 8; ++i) {
#pragma unroll
    for (int jj = 0; jj < 4; ++jj) {
      int r = rowBase + wm * 128 + i * 16 + lrow4 + jj;
      float rz = rinv[r] / Zb[r];
#pragma unroll
      for (int j = 0; j < 4; ++j) {
        int c = colBase + wn * 64 + j * 16 + lcol;
        outf[(size_t)r * D_ + c] = acc[i][j][jj] * rz;
      }
    }
  }
}

// ---------------------------------------------------------------- launch
extern "C" void kernel_launch(void* const* d_in, const int* in_sizes, int n_in,
                              void* d_out, int out_size, void* d_ws, size_t ws_size,
                              hipStream_t stream) {
  const float* x = (const float*)d_in[0];
  const float* Wq = (const float*)d_in[1];
  const float* bq = (const float*)d_in[2];
  const float* Wk = (const float*)d_in[3];
  const float* bk = (const float*)d_in[4];
  const float* Wv = (const float*)d_in[5];
  const float* bv = (const float*)d_in[6];
  const float* rot = (const float*)d_in[7];

  char* ws = (char*)d_ws;
  size_t off = 0;
  auto take = [&](size_t bytes) {
    char* p = ws + off;
    off += (bytes + 255) & ~(size_t)255;
    return p;
  };
  u16* xb = (u16*)take((size_t)BN_ * S_ * D_ * 2);        // 32 MB
  u16* wcat = (u16*)take((size_t)3 * D_ * D_ * 2);        // 6 MB (Wq|Wk|Wv)
  float* bcat = (float*)take((size_t)3 * D_ * 4);
  u16* qb = (u16*)take((size_t)BN_ * S_ * D_ * 2);        // 32 MB
  u16* kbuf = (u16*)take((size_t)BN_ * S_ * D_ * 2);      // 32 MB
  u16* vtb = (u16*)take((size_t)BN_ * S_ * D_ * 2);       // 32 MB (B,D,S)
  u16* hyb = (u16*)take((size_t)BN_ * S_ * S_ * 2);       // 64 MB
  u16* msk = (u16*)take((size_t)S_ * S_ * 2);             // 8.4 MB
  float* Zb = (float*)take((size_t)BN_ * S_ * 4);
  float* rinv = (float*)take((size_t)S_ * 4);

  (void)hipMemsetAsync(Zb, 0, (size_t)BN_ * S_ * 4, stream);

  cvt_bf16<<<2048, 256, 0, stream>>>(x, xb, BN_ * S_ * D_ / 8);
  cvt_wb<<<1548, 256, 0, stream>>>(Wq, Wk, Wv, bq, bk, bv, wcat, bcat);
  mask_kernel<<<S_, 256, 0, stream>>>(rot, msk, rinv);

  gemm_qkv8<<<768, 512, 0, stream>>>(xb, wcat, bcat, qb, kbuf, vtb);

  score8<<<512, 512, 0, stream>>>(qb, kbuf, msk, hyb, Zb);

  gemm_pv8<<<256, 512, 0, stream>>>(hyb, vtb, Zb, rinv, (float*)d_out);
}

// Round 12
// 295.299 us; speedup vs baseline: 1.0701x; 1.0019x over previous
//
#include <hip/hip_runtime.h>

typedef unsigned short u16;
typedef u16 u16x4 __attribute__((ext_vector_type(4)));
typedef u16 u16x8 __attribute__((ext_vector_type(8)));
typedef __bf16 bf16x8 __attribute__((ext_vector_type(8)));
typedef float f32x4 __attribute__((ext_vector_type(4)));

#define GL2LDS(gp, lp)                                                          \
  __builtin_amdgcn_global_load_lds(                                             \
      (const __attribute__((address_space(1))) void*)(gp),                      \
      (__attribute__((address_space(3))) void*)(lp), 16, 0, 0)

__device__ __forceinline__ u16 f2bf(float f) {
  unsigned u = __builtin_bit_cast(unsigned, f);
  u += 0x7fffu + ((u >> 16) & 1u);
  return (u16)(u >> 16);
}

__device__ __forceinline__ float bf2f(u16 v) {
  unsigned u = ((unsigned)v) << 16;
  return __builtin_bit_cast(float, u);
}

__device__ __forceinline__ f32x4 mfma_bf16(u16x8 a, u16x8 b, f32x4 c) {
  return __builtin_amdgcn_mfma_f32_16x16x32_bf16(
      __builtin_bit_cast(bf16x8, a), __builtin_bit_cast(bf16x8, b), c, 0, 0, 0);
}

constexpr int BN_ = 8;      // batch
constexpr int S_ = 2048;    // seq
constexpr int D_ = 1024;    // embed

// ---------------------------------------------------------------- small kernels
__global__ __launch_bounds__(256) void cvt_bf16(const float* __restrict__ in,
                                                u16* __restrict__ out, int n8) {
  int i = blockIdx.x * blockDim.x + threadIdx.x;
  int stride = gridDim.x * blockDim.x;
  for (; i < n8; i += stride) {
    const float4* p = reinterpret_cast<const float4*>(in) + (size_t)i * 2;
    float4 a = p[0], b = p[1];
    u16x8 o;
    o[0] = f2bf(a.x); o[1] = f2bf(a.y); o[2] = f2bf(a.z); o[3] = f2bf(a.w);
    o[4] = f2bf(b.x); o[5] = f2bf(b.y); o[6] = f2bf(b.z); o[7] = f2bf(b.w);
    reinterpret_cast<u16x8*>(out)[i] = o;
  }
}

// converts Wq|Wk|Wv -> wcat (bf16) and concats biases -> bcat in ONE dispatch
__global__ __launch_bounds__(256) void cvt_wb(const float* __restrict__ Wq,
                                              const float* __restrict__ Wk,
                                              const float* __restrict__ Wv,
                                              const float* __restrict__ bq,
                                              const float* __restrict__ bk,
                                              const float* __restrict__ bv,
                                              u16* __restrict__ wcat,
                                              float* __restrict__ bcat) {
  const int bid = blockIdx.x, t = threadIdx.x;
  if (bid < 1536) {
    const int idx = bid * 256 + t;        // u16x8 index, 0..393215
    const int w = idx >> 17;              // which weight (131072 u16x8 each)
    const int off = idx & 131071;
    const float* src = (w == 0) ? Wq : (w == 1) ? Wk : Wv;
    const float4* p = reinterpret_cast<const float4*>(src) + (size_t)off * 2;
    float4 a = p[0], b = p[1];
    u16x8 o;
    o[0] = f2bf(a.x); o[1] = f2bf(a.y); o[2] = f2bf(a.z); o[3] = f2bf(a.w);
    o[4] = f2bf(b.x); o[5] = f2bf(b.y); o[6] = f2bf(b.z); o[7] = f2bf(b.w);
    reinterpret_cast<u16x8*>(wcat)[idx] = o;
  } else {
    const int j = (bid - 1536) * 256 + t;  // 0..3071
    bcat[j] = (j < 1024) ? bq[j] : (j < 2048) ? bk[j - 1024] : bv[j - 2048];
  }
}

// msk[r][c] = bf16(rot[r][c]^2); rinv[r] = 1 / max(sum_c rot^2, EPS^2)
__global__ __launch_bounds__(256) void mask_kernel(const float* __restrict__ rot,
                                                   u16* __restrict__ msk,
                                                   float* __restrict__ rinv) {
  int r = blockIdx.x, t = threadIdx.x;
  const float4* p = reinterpret_cast<const float4*>(rot + (size_t)r * S_);
  float4 a = p[t], b = p[t + 256];
  float ax = a.x * a.x, ay = a.y * a.y, az = a.z * a.z, aw = a.w * a.w;
  float bx = b.x * b.x, by = b.y * b.y, bz = b.z * b.z, bw = b.w * b.w;
  u16x4 oa, ob;
  oa[0] = f2bf(ax); oa[1] = f2bf(ay); oa[2] = f2bf(az); oa[3] = f2bf(aw);
  ob[0] = f2bf(bx); ob[1] = f2bf(by); ob[2] = f2bf(bz); ob[3] = f2bf(bw);
  u16* mrow = msk + (size_t)r * S_;
  *reinterpret_cast<u16x4*>(mrow + t * 4) = oa;
  *reinterpret_cast<u16x4*>(mrow + 1024 + t * 4) = ob;
  float s = ax + ay + az + aw + bx + by + bz + bw;
#pragma unroll
  for (int d = 1; d < 64; d <<= 1) s += __shfl_xor(s, d);
  __shared__ float wsum[4];
  if ((t & 63) == 0) wsum[t >> 6] = s;
  __syncthreads();
  if (t == 0) {
    float ss = wsum[0] + wsum[1] + wsum[2] + wsum[3];
    rinv[r] = 1.0f / fmaxf(ss, 1e-24f);
  }
}

// ---------------------------------------------------------------- 8-phase K-loop core
// 256x256 tile, BK=64, 8 waves (2M x 4N); LDS 128 KB: 2 buf x {A,B} x {k0,k1}
// regions of [256 rows][32 u16]. Linear DMA dest + inverse-swizzled global source
// + swizzled ds_read. Swizzle (corrected R12): 16B slot sl = s ^ ((row>>1)&3) --
// full 2-bit XOR makes each 16-lane read group 2-way bank-aliased (free, m136);
// the old 1-bit variant left 4-way conflicts (262K/dispatch). Stage-side inverse:
// tr = t ^ ((t>>3)&3) (bijective, row bits untouched). vmcnt(6) at phases 4,8
// only; never 0. Tail stages wrap (kt & (NK-1)): counts stay uniform so vmcnt
// landing guarantees hold; junk lands only in regions never read again
// (LDS-reusing epilogues fence with __syncthreads(), implicit vmcnt(0)).
template <int NK>
__device__ __forceinline__ void kloop8(const u16* __restrict__ Abase,
                                       const u16* __restrict__ Bbase,
                                       int sA, int sB, u16* sh,
                                       f32x4 (&acc)[8][4]) {
  const int t = threadIdx.x;
  const int lane = t & 63, w = t >> 6;
  const int wm = w >> 2, wn = w & 3;
  const int lr = lane & 15;
  const int sl = (lane >> 4) ^ ((lr >> 1) & 3);          // corrected swizzled slot
  const int aOff = (wm * 128 + lr) * 32 + sl * 8;        // u16, within (P,kk) region
  const int bOff = 16384 + (wn * 64 + lr) * 32 + sl * 8; // + B-op offset

  // stage source precompute (inverse swizzle on global address)
  const int tr = t ^ ((t >> 3) & 3);
  const u16* aSrc = Abase + (size_t)(tr >> 2) * sA + (tr & 3) * 8;
  const u16* bSrc = Bbase + (size_t)(tr >> 2) * sB + (tr & 3) * 8;
  const size_t a128 = (size_t)128 * sA, b128 = (size_t)128 * sB;
  u16* dBase = sh + t * 8;

  auto stage = [&](int P, int op, int kk, int kt) {
    kt &= (NK - 1);  // wrap at tail: uniform vmcnt counting, data unused
    const u16* s = (op ? bSrc : aSrc) + kt * 64 + kk * 32;
    u16* d = dBase + P * 32768 + op * 16384 + kk * 8192;
    GL2LDS(s, d);
    GL2LDS(s + (op ? b128 : a128), d + 4096);
  };

  u16x8 bf[4];

#define PHASE(P, kk, mh, sP, sOp, sKk, sKt, vm)                                  \
  do {                                                                           \
    stage(sP, sOp, sKk, sKt);                                                    \
    const u16* ap_ = sh + (P) * 32768 + (kk) * 8192 + aOff;                      \
    u16x8 af_[4];                                                                \
    _Pragma("unroll")                                                            \
    for (int i_ = 0; i_ < 4; ++i_)                                               \
      af_[i_] = *reinterpret_cast<const u16x8*>(ap_ + ((mh) * 4 + i_) * 512);    \
    if ((mh) == 0) {                                                             \
      const u16* bp_ = sh + (P) * 32768 + (kk) * 8192 + bOff;                    \
      _Pragma("unroll")                                                          \
      for (int j_ = 0; j_ < 4; ++j_)                                             \
        bf[j_] = *reinterpret_cast<const u16x8*>(bp_ + j_ * 512);                \
    }                                                                            \
    asm volatile("s_barrier" ::: "memory");                                      \
    __builtin_amdgcn_s_setprio(1);                                               \
    _Pragma("unroll")                                                            \
    for (int i_ = 0; i_ < 4; ++i_)                                               \
      _Pragma("unroll")                                                          \
      for (int j_ = 0; j_ < 4; ++j_)                                             \
        acc[(mh) * 4 + i_][j_] = mfma_bf16(af_[i_], bf[j_], acc[(mh) * 4 + i_][j_]); \
    __builtin_amdgcn_s_setprio(0);                                               \
    if (vm) asm volatile("s_waitcnt vmcnt(6)" ::: "memory");                     \
    asm volatile("s_barrier" ::: "memory");                                      \
  } while (0)

  // prologue: K0 fully, K1 all but A.k1 (staged by ph1); allow last 3 stages in flight
  stage(0, 1, 0, 0); stage(0, 0, 0, 0); stage(0, 1, 1, 0); stage(0, 0, 1, 0);
  stage(1, 1, 0, 1); stage(1, 0, 0, 1); stage(1, 1, 1, 1);
  asm volatile("s_waitcnt vmcnt(6)" ::: "memory");
  asm volatile("s_barrier" ::: "memory");

  for (int j2 = 0; j2 < NK / 2; ++j2) {
    const int kb = 2 * j2;
    PHASE(0, 0, 0, 1, 0, 1, kb + 1, false);  // stage P1.A.k1 <- ktile kb+1
    PHASE(0, 0, 1, 0, 1, 0, kb + 2, false);  // stage P0.B.k0 <- kb+2
    PHASE(0, 1, 0, 0, 0, 0, kb + 2, false);  // stage P0.A.k0 <- kb+2
    PHASE(0, 1, 1, 0, 1, 1, kb + 2, true);   // stage P0.B.k1 <- kb+2, vmcnt(6)
    PHASE(1, 0, 0, 0, 0, 1, kb + 2, false);  // stage P0.A.k1 <- kb+2
    PHASE(1, 0, 1, 1, 1, 0, kb + 3, false);  // stage P1.B.k0 <- kb+3
    PHASE(1, 1, 0, 1, 0, 0, kb + 3, false);  // stage P1.A.k0 <- kb+3
    PHASE(1, 1, 1, 1, 1, 1, kb + 3, true);   // stage P1.B.k1 <- kb+3, vmcnt(6)
  }
#undef PHASE
}

// ---------------------------------------------------------------- fused QKV (256^2, 8-phase)
// C = xb @ wcat^T + bcat; col-tiles 0-3 -> q, 4-7 -> k, 8-11 -> v (transposed to vt)
__global__ __launch_bounds__(512, 2)
void gemm_qkv8(const u16* __restrict__ xb, const u16* __restrict__ wcat,
               const float* __restrict__ bcat, u16* __restrict__ qb,
               u16* __restrict__ kb, u16* __restrict__ vtb) {
  __shared__ alignas(16) u16 sh[65536];
  const int lin = blockIdx.x;
  const int swz = (lin & 7) * 96 + (lin >> 3);   // 768 blocks, 8 XCDs
  const int rt = swz / 12, ct = swz - rt * 12;
  const int rowBase = rt << 8, colBase = ct << 8;

  f32x4 acc[8][4] = {};
  kloop8<16>(xb + (size_t)rowBase * D_, wcat + (size_t)colBase * D_, D_, D_, sh, acc);

  const int t = threadIdx.x;
  const int lane = t & 63, w = t >> 6;
  const int wm = w >> 2, wn = w & 3;
  const int lrow4 = (lane >> 4) * 4, lcol = lane & 15;

  float bias[4];
#pragma unroll
  for (int j = 0; j < 4; ++j) bias[j] = bcat[colBase + wn * 64 + j * 16 + lcol];

  const int cls = colBase >> 10;  // 0=q, 1=k, 2=v
  const int ccol = colBase & 1023;
  if (cls < 2) {
    u16* out16 = (cls == 0) ? qb : kb;
#pragma unroll
    for (int i = 0; i < 8; ++i) {
#pragma unroll
      for (int jj = 0; jj < 4; ++jj) {
        int r = rowBase + wm * 128 + i * 16 + lrow4 + jj;
#pragma unroll
        for (int j = 0; j < 4; ++j) {
          int c = ccol + wn * 64 + j * 16 + lcol;
          out16[(size_t)r * D_ + c] = f2bf(acc[i][j][jj] + bias[j]);
        }
      }
    }
  } else {
    // v: transpose 256x256 tile through LDS in two 128-row passes
    __syncthreads();  // drains vmcnt(0): in-flight wrap-stage junk lands before reuse
    u16 (*Ts)[136] = reinterpret_cast<u16(*)[136]>(sh);
    const int bq = rowBase >> 11, s0 = rowBase & (S_ - 1);
#pragma unroll
    for (int h = 0; h < 2; ++h) {
      if (wm == h) {
#pragma unroll
        for (int i = 0; i < 8; ++i)
#pragma unroll
          for (int jj = 0; jj < 4; ++jj)
#pragma unroll
            for (int j = 0; j < 4; ++j)
              Ts[wn * 64 + j * 16 + lcol][i * 16 + lrow4 + jj] =
                  f2bf(acc[i][j][jj] + bias[j]);
      }
      __syncthreads();
      const int col = t >> 1, ro = (t & 1) * 64;
      u16* dst = vtb + (size_t)bq * D_ * S_ + (size_t)(ccol + col) * S_ +
                 s0 + h * 128 + ro;
      const u16* srcp = &Ts[col][ro];
#pragma unroll
      for (int k2 = 0; k2 < 8; ++k2)
        *reinterpret_cast<u16x8*>(dst + k2 * 8) =
            *reinterpret_cast<const u16x8*>(srcp + k2 * 8);
      __syncthreads();
    }
  }
}

// ---------------------------------------------------------------- scores (256^2, 8-phase)
// logits = q @ k^T / 32; hyb = exp(l)*msk (bf16, unnormalized); Z[b,row] += sum exp(l)
__global__ __launch_bounds__(512, 2)
void score8(const u16* __restrict__ qb, const u16* __restrict__ kb,
            const u16* __restrict__ msk, u16* __restrict__ hyb,
            float* __restrict__ Z) {
  __shared__ alignas(16) u16 sh[65536];
  const int lin = blockIdx.x;
  const int swz = (lin & 7) * 64 + (lin >> 3);   // 512 blocks; one batch per XCD
  const int b = swz >> 6, rt = (swz >> 3) & 7, ct = swz & 7;
  const int rowBase = rt << 8, colBase = ct << 8;

  f32x4 acc[8][4] = {};
  kloop8<16>(qb + ((size_t)(b * S_ + rowBase)) * D_,
             kb + ((size_t)(b * S_ + colBase)) * D_, D_, D_, sh, acc);

  const int t = threadIdx.x;
  const int lane = t & 63, w = t >> 6;
  const int wm = w >> 2, wn = w & 3;
  const int lrow4 = (lane >> 4) * 4, lcol = lane & 15;

#pragma unroll
  for (int i = 0; i < 8; ++i) {
    const int rowL = rowBase + wm * 128 + i * 16 + lrow4;
    f32x4 zrow = {0.f, 0.f, 0.f, 0.f};
#pragma unroll
    for (int j = 0; j < 4; ++j) {
      const int col = colBase + wn * 64 + j * 16 + lcol;
#pragma unroll
      for (int jj = 0; jj < 4; ++jj) {
        const int row = rowL + jj;
        float e = __expf(acc[i][j][jj] * 0.03125f);
        hyb[((size_t)(b * S_ + row)) * S_ + col] =
            f2bf(e * bf2f(msk[(size_t)row * S_ + col]));
        zrow[jj] += e;
      }
    }
#pragma unroll
    for (int d = 1; d < 16; d <<= 1) {
      zrow[0] += __shfl_xor(zrow[0], d);
      zrow[1] += __shfl_xor(zrow[1], d);
      zrow[2] += __shfl_xor(zrow[2], d);
      zrow[3] += __shfl_xor(zrow[3], d);
    }
    if (lcol == 0) {
#pragma unroll
      for (int jj = 0; jj < 4; ++jj)
        atomicAdd(&Z[b * S_ + rowL + jj], zrow[jj]);
    }
  }
}

// ---------------------------------------------------------------- PV (256^2, 8-phase)
// out[b] = (hyb[b] @ vt[b]^T-layout) * rinv[r] / Z[b][r]
__global__ __launch_bounds__(512, 2)
void gemm_pv8(const u16* __restrict__ hyb, const u16* __restrict__ vtb,
              const float* __restrict__ Z, const float* __restrict__ rinv,
              float* __restrict__ outp) {
  __shared__ alignas(16) u16 sh[65536];
  const int lin = blockIdx.x;
  const int swz = (lin & 7) * 32 + (lin >> 3);   // 256 blocks; one batch per XCD
  const int b = swz >> 5, rt = (swz >> 2) & 7, ct = swz & 3;
  const int rowBase = rt << 8, colBase = ct << 8;

  f32x4 acc[8][4] = {};
  kloop8<32>(hyb + (size_t)b * S_ * S_ + (size_t)rowBase * S_,
             vtb + (size_t)b * D_ * S_ + (size_t)colBase * S_, S_, S_, sh, acc);

  const int t = threadIdx.x;
  const int lane = t & 63, w = t >> 6;
  const int wm = w >> 2, wn = w & 3;
  const int lrow4 = (lane >> 4) * 4, lcol = lane & 15;

  float* outf = outp + (size_t)b * S_ * D_;
  const float* Zb = Z + (size_t)b * S_;
#pragma unroll
  for (int i = 0; i < 8; ++i) {
#pragma unroll
    for (int jj = 0; jj < 4; ++jj) {
      int r = rowBase + wm * 128 + i * 16 + lrow4 + jj;
      float rz = rinv[r] / Zb[r];
#pragma unroll
      for (int j = 0; j < 4; ++j) {
        int c = colBase + wn * 64 + j * 16 + lcol;
        outf[(size_t)r * D_ + c] = acc[i][j][jj] * rz;
      }
    }
  }
}

// ---------------------------------------------------------------- launch
extern "C" void kernel_launch(void* const* d_in, const int* in_sizes, int n_in,
                              void* d_out, int out_size, void* d_ws, size_t ws_size,
                              hipStream_t stream) {
  const float* x = (const float*)d_in[0];
  const float* Wq = (const float*)d_in[1];
  const float* bq = (const float*)d_in[2];
  const float* Wk = (const float*)d_in[3];
  const float* bk = (const float*)d_in[4];
  const float* Wv = (const float*)d_in[5];
  const float* bv = (const float*)d_in[6];
  const float* rot = (const float*)d_in[7];

  char* ws = (char*)d_ws;
  size_t off = 0;
  auto take = [&](size_t bytes) {
    char* p = ws + off;
    off += (bytes + 255) & ~(size_t)255;
    return p;
  };
  u16* xb = (u16*)take((size_t)BN_ * S_ * D_ * 2);        // 32 MB
  u16* wcat = (u16*)take((size_t)3 * D_ * D_ * 2);        // 6 MB (Wq|Wk|Wv)
  float* bcat = (float*)take((size_t)3 * D_ * 4);
  u16* qb = (u16*)take((size_t)BN_ * S_ * D_ * 2);        // 32 MB
  u16* kbuf = (u16*)take((size_t)BN_ * S_ * D_ * 2);      // 32 MB
  u16* vtb = (u16*)take((size_t)BN_ * S_ * D_ * 2);       // 32 MB (B,D,S)
  u16* hyb = (u16*)take((size_t)BN_ * S_ * S_ * 2);       // 64 MB
  u16* msk = (u16*)take((size_t)S_ * S_ * 2);             // 8.4 MB
  float* Zb = (float*)take((size_t)BN_ * S_ * 4);
  float* rinv = (float*)take((size_t)S_ * 4);

  (void)hipMemsetAsync(Zb, 0, (size_t)BN_ * S_ * 4, stream);

  cvt_bf16<<<2048, 256, 0, stream>>>(x, xb, BN_ * S_ * D_ / 8);
  cvt_wb<<<1548, 256, 0, stream>>>(Wq, Wk, Wv, bq, bk, bv, wcat, bcat);
  mask_kernel<<<S_, 256, 0, stream>>>(rot, msk, rinv);

  gemm_qkv8<<<768, 512, 0, stream>>>(xb, wcat, bcat, qb, kbuf, vtb);

  score8<<<512, 512, 0, stream>>>(qb, kbuf, msk, hyb, Zb);

  gemm_pv8<<<256, 512, 0, stream>>>(hyb, vtb, Zb, rinv, (float*)d_out);
}